// Round 8
// baseline (1130.971 us; speedup 1.0000x reference)
//
#include <hip/hip_runtime.h>
#include <cstddef>
#include <cstdint>

#define B_ 64
#define N_ 128
#define FIN_ 768
#define NEG_E_ (-9.0e15f)
#define NEG_S_ (-9.0e10f)
#define CHUNK_ 16

typedef unsigned short u16;
typedef unsigned int u32;
typedef float f32x4 __attribute__((ext_vector_type(4)));
typedef short s16x8 __attribute__((ext_vector_type(8)));   // 8 bf16 frag
typedef u16 u16x4 __attribute__((ext_vector_type(4)));

__device__ __forceinline__ u16 f2bf(float x) {
  u32 u = __float_as_uint(x);
  return (u16)((u + 0x7fffu + ((u >> 16) & 1u)) >> 16);
}
__device__ __forceinline__ float b2f(u16 h) {
  return __uint_as_float(((u32)h) << 16);
}

// ---------------------------------------------------------------------------
// Group pooling, k-sequential scan form (R7-verified).
// ---------------------------------------------------------------------------
__global__ __launch_bounds__(128) void group_pool_kernel(
    const float* __restrict__ x, const int* __restrict__ offs,
    u16* __restrict__ xoh, u16* __restrict__ xol, int* __restrict__ ig)
{
  const int b = blockIdx.x;
  const int fc = blockIdx.y;
  const int tid = threadIdx.x;
  __shared__ int o0[N_], o1[N_];
  __shared__ int bnd[N_];
  __shared__ float invlen[N_];
  __shared__ int st[N_], en[N_];
  __shared__ int Gs;
  o0[tid] = offs[(b * N_ + tid) * 2 + 0];
  o1[tid] = offs[(b * N_ + tid) * 2 + 1];
  bnd[tid] = -1;
  __syncthreads();
  if (tid == 0) {
    int fz = N_;
    for (int k = 0; k < N_; ++k) { if (o0[k] == 0 && o1[k] == 0) { fz = k; break; } }
    int g = 0, prev = 0;
    for (int k = 0; k < fz; ++k) {
      int nxt = (k + 1 < N_) ? o0[k + 1] : 0;
      if (o1[k] == nxt - 1 && g < N_) {
        bnd[k] = g;
        invlen[g] = 1.0f / (float)(k + 1 - prev);
        st[g] = prev;
        en[g] = k + 1;
        prev = k + 1;
        ++g;
      }
    }
    Gs = g;
  }
  __syncthreads();
  const int G = Gs;
  const int f = fc * 128 + tid;
  const float* xb = x + (size_t)b * N_ * FIN_ + f;
  float acc = 0.0f;
  for (int k0 = 0; k0 < N_; k0 += 8) {
    float v[8];
#pragma unroll
    for (int u = 0; u < 8; ++u) v[u] = xb[(size_t)(k0 + u) * FIN_];
#pragma unroll
    for (int u = 0; u < 8; ++u) {
      acc += v[u];
      int g = bnd[k0 + u];
      if (g >= 0) {
        float mean = acc * invlen[g];
        u16 hh = f2bf(mean);
        size_t oo = ((size_t)b * N_ + g) * FIN_ + f;
        xoh[oo] = hh;
        xol[oo] = f2bf(mean - b2f(hh));
        acc = 0.0f;
      }
    }
  }
  for (int g = G; g < N_; ++g) {
    size_t oo = ((size_t)b * N_ + g) * FIN_ + f;
    xoh[oo] = 0;
    xol[oo] = 0;
  }
  if (fc == 0) {
    int g = tid;
    ig[(b * N_ + g) * 2 + 0] = (g < G) ? st[g] : 0;
    ig[(b * N_ + g) * 2 + 1] = (g < G) ? en[g] : 0;
  }
}

// ---------------------------------------------------------------------------
// Weight pack/transpose/split kernels
// ---------------------------------------------------------------------------
__global__ __launch_bounds__(256) void pack_wgT(
    const float* __restrict__ w, u16* __restrict__ th, u16* __restrict__ tl)
{
  int idx = blockIdx.x * 256 + threadIdx.x;
  float v = w[idx];
  int k = idx >> 10, n = idx & 1023;
  u16 h = f2bf(v);
  th[n * 768 + k] = h;
  tl[n * 768 + k] = f2bf(v - b2f(h));
}
__global__ __launch_bounds__(256) void pack_hwT(
    const float* __restrict__ w, u16* __restrict__ th, u16* __restrict__ tl)
{
  int idx = blockIdx.x * 256 + threadIdx.x;
  float v = w[idx];
  int hd = idx >> 19, f = (idx >> 9) & 1023, o = idx & 511;
  int dst = (hd * 512 + o) * 1024 + f;
  u16 h = f2bf(v);
  th[dst] = h;
  tl[dst] = f2bf(v - b2f(h));
}
__global__ __launch_bounds__(256) void pack_owT(
    const float* __restrict__ w, u16* __restrict__ th, u16* __restrict__ tl)
{
  int idx = blockIdx.x * 256 + threadIdx.x;
  float v = w[idx];
  int k = idx >> 9, o = idx & 511;
  int dst = o * 4096 + k;
  u16 h = f2bf(v);
  th[dst] = h;
  tl[dst] = f2bf(v - b2f(h));
}

// ---------------------------------------------------------------------------
// Split-bf16 MFMA GEMM, register-prefetch pipeline + LDS-transpose epilogue
// (coalesced stores: 32-64 B contiguous per lane; lane-quads cover full lines).
// ---------------------------------------------------------------------------
__global__ __launch_bounds__(256) void mfma_split_gemm(
    const u16* __restrict__ Ah, const u16* __restrict__ Al,
    const u16* __restrict__ Bh, const u16* __restrict__ Bl,
    const float* __restrict__ bias, int bias_mode,   // 0 none, 1 per-n, 2 per-m
    u16* __restrict__ Oh, u16* __restrict__ Ol, float* __restrict__ Of,
    int out_f32, int do_elu,
    int K, int lda, int ldb,
    long long Az, long long Bz,
    int msh, long long s_mb, int nsh, long long s_nb, long long s_n,
    long long zb_s, long long zh_s, int zH)
{
  __shared__ u16 As_h[128][40];
  __shared__ u16 As_l[128][40];
  __shared__ u16 Bs_h[128][40];
  __shared__ u16 Bs_l[128][40];
  const int tid = threadIdx.x;
  const int wave = tid >> 6, lane = tid & 63;
  const int wm = (wave >> 1) * 64, wn = (wave & 1) * 64;
  const int bn = blockIdx.x * 128, bm = blockIdx.y * 128;
  const int z = blockIdx.z;
  const u16* Ahb = Ah + (long long)z * Az;
  const u16* Alb = Al + (long long)z * Az;
  const u16* Bhb = Bh + (long long)z * Bz;
  const u16* Blb = Bl + (long long)z * Bz;
  const int lm = lane & 15, lq = lane >> 4;

  const int sr = tid >> 1;
  const int sc = (tid & 1) * 16;
  const size_t ga = (size_t)(bm + sr) * lda + sc;
  const size_t gb = (size_t)(bn + sr) * ldb + sc;

  f32x4 acc[4][4];
#pragma unroll
  for (int i = 0; i < 4; ++i)
#pragma unroll
    for (int j = 0; j < 4; ++j) acc[i][j] = (f32x4){0.0f, 0.0f, 0.0f, 0.0f};

  uint4 r0, r1, r2, r3, r4, r5, r6, r7;
  r0 = *(const uint4*)(Ahb + ga);
  r1 = *(const uint4*)(Ahb + ga + 8);
  r2 = *(const uint4*)(Alb + ga);
  r3 = *(const uint4*)(Alb + ga + 8);
  r4 = *(const uint4*)(Bhb + gb);
  r5 = *(const uint4*)(Bhb + gb + 8);
  r6 = *(const uint4*)(Blb + gb);
  r7 = *(const uint4*)(Blb + gb + 8);

  for (int k0 = 0; k0 < K; k0 += 32) {
    __syncthreads();
    *(uint4*)&As_h[sr][sc] = r0;
    *(uint4*)&As_h[sr][sc + 8] = r1;
    *(uint4*)&As_l[sr][sc] = r2;
    *(uint4*)&As_l[sr][sc + 8] = r3;
    *(uint4*)&Bs_h[sr][sc] = r4;
    *(uint4*)&Bs_h[sr][sc + 8] = r5;
    *(uint4*)&Bs_l[sr][sc] = r6;
    *(uint4*)&Bs_l[sr][sc + 8] = r7;
    __syncthreads();
    int kn = k0 + 32;
    if (kn < K) {
      r0 = *(const uint4*)(Ahb + ga + kn);
      r1 = *(const uint4*)(Ahb + ga + kn + 8);
      r2 = *(const uint4*)(Alb + ga + kn);
      r3 = *(const uint4*)(Alb + ga + kn + 8);
      r4 = *(const uint4*)(Bhb + gb + kn);
      r5 = *(const uint4*)(Bhb + gb + kn + 8);
      r6 = *(const uint4*)(Blb + gb + kn);
      r7 = *(const uint4*)(Blb + gb + kn + 8);
    }
    s16x8 fa_h[4], fa_l[4], fb_h[4], fb_l[4];
#pragma unroll
    for (int t = 0; t < 4; ++t) {
      fa_h[t] = *(const s16x8*)&As_h[wm + t * 16 + lm][lq * 8];
      fa_l[t] = *(const s16x8*)&As_l[wm + t * 16 + lm][lq * 8];
      fb_h[t] = *(const s16x8*)&Bs_h[wn + t * 16 + lm][lq * 8];
      fb_l[t] = *(const s16x8*)&Bs_l[wn + t * 16 + lm][lq * 8];
    }
#pragma unroll
    for (int i = 0; i < 4; ++i)
#pragma unroll
      for (int j = 0; j < 4; ++j) {
        acc[i][j] = __builtin_amdgcn_mfma_f32_16x16x32_bf16(fa_h[i], fb_h[j], acc[i][j], 0, 0, 0);
        acc[i][j] = __builtin_amdgcn_mfma_f32_16x16x32_bf16(fa_h[i], fb_l[j], acc[i][j], 0, 0, 0);
        acc[i][j] = __builtin_amdgcn_mfma_f32_16x16x32_bf16(fa_l[i], fb_h[j], acc[i][j], 0, 0, 0);
      }
  }

  // ---- LDS-transpose epilogue ----
  __syncthreads();   // all waves done with As/Bs; reuse as scratch
  const long long zoff = (long long)(z / zH) * zb_s + (long long)(z % zH) * zh_s;
  const int mmask = (1 << msh) - 1;
  const int nmask = (1 << nsh) - 1;
  char* lds_raw = (char*)&As_h[0][0] + wave * 4608;   // private per-wave slab
  const int rn = lane >> 2;             // read-phase n_local (0..15)
  const int rm = (lane & 3) * 16;       // read-phase m offset (0..48)

  if (out_f32) {
    float* slab = (float*)lds_raw;      // [16][68] floats (272 B rows, 16B-mult)
#pragma unroll
    for (int j = 0; j < 4; ++j) {
#pragma unroll
      for (int i = 0; i < 4; ++i) {
        int mb = bm + wm + i * 16 + lq * 4;
        int n = bn + wn + j * 16 + lm;
        f32x4 v = acc[i][j];
        if (bias_mode == 1) v += bias[n];
        else if (bias_mode == 2) { f32x4 b4 = *(const f32x4*)&bias[mb]; v += b4; }
        if (do_elu) {
          v.x = v.x > 0.0f ? v.x : expm1f(v.x);
          v.y = v.y > 0.0f ? v.y : expm1f(v.y);
          v.z = v.z > 0.0f ? v.z : expm1f(v.z);
          v.w = v.w > 0.0f ? v.w : expm1f(v.w);
        }
        *(f32x4*)&slab[lm * 68 + i * 16 + lq * 4] = v;
      }
      __syncthreads();
      int n = bn + wn + j * 16 + rn;
      int mbase = bm + wm + rm;
      long long off = (long long)(mbase >> msh) * s_mb + (mbase & mmask)
                    + (long long)(n >> nsh) * s_nb + (long long)(n & nmask) * s_n + zoff;
      const float* src = &slab[rn * 68 + rm];
      f32x4 v0 = *(const f32x4*)(src + 0);
      f32x4 v1 = *(const f32x4*)(src + 4);
      f32x4 v2 = *(const f32x4*)(src + 8);
      f32x4 v3 = *(const f32x4*)(src + 12);
      *(f32x4*)(Of + off + 0)  = v0;
      *(f32x4*)(Of + off + 4)  = v1;
      *(f32x4*)(Of + off + 8)  = v2;
      *(f32x4*)(Of + off + 12) = v3;
      __syncthreads();
    }
  } else {
    u16* slab_h = (u16*)lds_raw;        // [16][72] u16 (144 B rows, 16B-mult)
    u16* slab_l = slab_h + 16 * 72;
#pragma unroll
    for (int j = 0; j < 4; ++j) {
#pragma unroll
      for (int i = 0; i < 4; ++i) {
        int mb = bm + wm + i * 16 + lq * 4;
        int n = bn + wn + j * 16 + lm;
        f32x4 v = acc[i][j];
        if (bias_mode == 1) v += bias[n];
        else if (bias_mode == 2) { f32x4 b4 = *(const f32x4*)&bias[mb]; v += b4; }
        if (do_elu) {
          v.x = v.x > 0.0f ? v.x : expm1f(v.x);
          v.y = v.y > 0.0f ? v.y : expm1f(v.y);
          v.z = v.z > 0.0f ? v.z : expm1f(v.z);
          v.w = v.w > 0.0f ? v.w : expm1f(v.w);
        }
        u16 h0 = f2bf(v.x), h1 = f2bf(v.y), h2 = f2bf(v.z), h3 = f2bf(v.w);
        u16x4 hv = {h0, h1, h2, h3};
        u16x4 lv = {f2bf(v.x - b2f(h0)), f2bf(v.y - b2f(h1)),
                    f2bf(v.z - b2f(h2)), f2bf(v.w - b2f(h3))};
        *(u16x4*)&slab_h[lm * 72 + i * 16 + lq * 4] = hv;
        *(u16x4*)&slab_l[lm * 72 + i * 16 + lq * 4] = lv;
      }
      __syncthreads();
      int n = bn + wn + j * 16 + rn;
      int mbase = bm + wm + rm;
      long long off = (long long)(mbase >> msh) * s_mb + (mbase & mmask)
                    + (long long)(n >> nsh) * s_nb + (long long)(n & nmask) * s_n + zoff;
      const u16* sh = &slab_h[rn * 72 + rm];
      const u16* sl = &slab_l[rn * 72 + rm];
      uint4 h0 = *(const uint4*)(sh + 0);
      uint4 h1 = *(const uint4*)(sh + 8);
      uint4 l0 = *(const uint4*)(sl + 0);
      uint4 l1 = *(const uint4*)(sl + 8);
      *(uint4*)(Oh + off + 0) = h0;
      *(uint4*)(Oh + off + 8) = h1;
      *(uint4*)(Ol + off + 0) = l0;
      *(uint4*)(Ol + off + 8) = l1;
      __syncthreads();
    }
  }
}

// ---------------------------------------------------------------------------
// Split-K reduces.
// ---------------------------------------------------------------------------
__global__ __launch_bounds__(256) void reduce2_split(
    const float* __restrict__ ps, const float* __restrict__ bias,
    u16* __restrict__ oh, u16* __restrict__ ol)
{
  int base = (blockIdx.x * 256 + threadIdx.x) * 4;   // 2048*1024 elements
  int feat = base & 1023;
  f32x4 v = *(const f32x4*)(ps + base);
  v += *(const f32x4*)(ps + base + 2097152);
  v += *(const f32x4*)(bias + feat);
  u16 h0 = f2bf(v.x), h1 = f2bf(v.y), h2 = f2bf(v.z), h3 = f2bf(v.w);
  u16x4 hv = {h0, h1, h2, h3};
  u16x4 lv = {f2bf(v.x - b2f(h0)), f2bf(v.y - b2f(h1)),
              f2bf(v.z - b2f(h2)), f2bf(v.w - b2f(h3))};
  *(u16x4*)(oh + base) = hv;
  *(u16x4*)(ol + base) = lv;
}

__global__ __launch_bounds__(256) void reduce4_bias(
    const float* __restrict__ ps, const float* __restrict__ bias,
    float* __restrict__ h2T, int col0)
{
  int base = (blockIdx.x * 256 + threadIdx.x) * 4;   // 512*2048 elements
  int o = base >> 11, m = base & 2047;
  f32x4 v = *(const f32x4*)(ps + base);
  v += *(const f32x4*)(ps + base + 1048576);
  v += *(const f32x4*)(ps + base + 2097152);
  v += *(const f32x4*)(ps + base + 3145728);
  v += bias[o];
  *(f32x4*)(h2T + (size_t)o * 8192 + col0 + m) = v;
}

// ---------------------------------------------------------------------------
// esrc/edst from hT (split bf16): block per (bc,head), 512 threads.
// ---------------------------------------------------------------------------
__global__ __launch_bounds__(512) void dot_pairs_hT(
    const u16* __restrict__ hTh, const u16* __restrict__ hTl,
    const float* __restrict__ W,   // ha_w [8][1024]
    float* __restrict__ esrc, float* __restrict__ edst)
{
  int bh = blockIdx.x;
  int head = bh & 7;
  int tid = threadIdx.x;
  int os = tid >> 7, i = tid & 127;
  const u16* ph = hTh + (size_t)bh * 65536 + (size_t)os * 16384 + i;
  const u16* pl = hTl + (size_t)bh * 65536 + (size_t)os * 16384 + i;
  const float* w1 = W + head * 1024 + os * 128;
  float s1 = 0.0f, s2 = 0.0f;
#pragma unroll 8
  for (int o = 0; o < 128; ++o) {
    float hv = b2f(ph[o * 128]) + b2f(pl[o * 128]);
    s1 = fmaf(hv, w1[o], s1);
    s2 = fmaf(hv, w1[512 + o], s2);
  }
  __shared__ float sh1[4][128], sh2[4][128];
  sh1[os][i] = s1;
  sh2[os][i] = s2;
  __syncthreads();
  if (os == 0) {
    esrc[bh * 128 + i] = sh1[0][i] + sh1[1][i] + sh1[2][i] + sh1[3][i];
    edst[bh * 128 + i] = sh2[0][i] + sh2[1][i] + sh2[2][i] + sh2[3][i];
  }
}

// e2 dots from h2T (fp32): block per b, 512 threads.
__global__ __launch_bounds__(512) void dot_pairs_h2T(
    const float* __restrict__ h2T, const float* __restrict__ oa,
    float* __restrict__ e2s, float* __restrict__ e2d)
{
  int b = blockIdx.x;
  int tid = threadIdx.x;
  int os = tid >> 7, i = tid & 127;
  const float* hb = h2T + (size_t)os * 128 * 8192 + b * 128 + i;
  const float* oa1 = oa + os * 128;
  float s1 = 0.0f, s2 = 0.0f;
#pragma unroll 8
  for (int o = 0; o < 128; ++o) {
    float hv = hb[(size_t)o * 8192];
    s1 = fmaf(hv, oa1[o], s1);
    s2 = fmaf(hv, oa1[512 + o], s2);
  }
  __shared__ float sh1[4][128], sh2[4][128];
  sh1[os][i] = s1;
  sh2[os][i] = s2;
  __syncthreads();
  if (os == 0) {
    e2s[b * 128 + i] = sh1[0][i] + sh1[1][i] + sh1[2][i] + sh1[3][i];
    e2d[b * 128 + i] = sh2[0][i] + sh2[1][i] + sh2[2][i] + sh2[3][i];
  }
}

// ---------------------------------------------------------------------------
// Edge softmax; split=1 -> bf16 hi/lo output, else fp32.  adj pre-offset.
// ---------------------------------------------------------------------------
__global__ __launch_bounds__(64) void edge_softmax_kernel(
    const float* __restrict__ esrc, const float* __restrict__ edst,
    const float* __restrict__ bias, const float* __restrict__ adj,
    float* __restrict__ attf, u16* __restrict__ atth, u16* __restrict__ attl,
    int H, int split)
{
  int row = blockIdx.x;
  int lane = threadIdx.x;
  int i = row & 127;
  int bh = row >> 7;
  int hd = bh % H;
  int b = bh / H;
  float es = esrc[row] + bias[hd];
  const float* adjr = adj + ((size_t)b * N_ + i) * N_;
  const float* edr = edst + (size_t)bh * N_;
  float v[2];
#pragma unroll
  for (int t = 0; t < 2; ++t) {
    int j = lane + t * 64;
    float e = es + edr[j];
    e = (e >= 0.0f) ? e : 0.2f * e;
    v[t] = (adjr[j] > 0.0f) ? e : NEG_E_;
  }
  float mx = fmaxf(v[0], v[1]);
  for (int off = 32; off; off >>= 1) mx = fmaxf(mx, __shfl_xor(mx, off));
  float e0 = expf(v[0] - mx), e1 = expf(v[1] - mx);
  float sm = e0 + e1;
  for (int off = 32; off; off >>= 1) sm += __shfl_xor(sm, off);
  float inv = 1.0f / sm;
  float p0 = e0 * inv, p1 = e1 * inv;
  size_t base = (size_t)row * N_;
  if (split) {
    u16 h0 = f2bf(p0), h1 = f2bf(p1);
    atth[base + lane] = h0;
    attl[base + lane] = f2bf(p0 - b2f(h0));
    atth[base + lane + 64] = h1;
    attl[base + lane + 64] = f2bf(p1 - b2f(h1));
  } else {
    attf[base + lane] = p0;
    attf[base + lane + 64] = p1;
  }
}

// ---------------------------------------------------------------------------
// Stage-2 fp32 batched GEMM + ELU (h2T[512][8192] B-layout).
// ---------------------------------------------------------------------------
__global__ __launch_bounds__(256) void bgemm_elu_bt_f32(
    const float* __restrict__ A, const float* __restrict__ BT,
    float* __restrict__ C)
{
  __shared__ float As[16][64];
  __shared__ float Bs[16][68];
  const int tid = threadIdx.x;
  const int tm = blockIdx.x >> 3, tn = blockIdx.x & 7;
  const int bm = tm * 64, bn = tn * 64;
  const int b = blockIdx.y;
  const float* Ab = A + (size_t)b * 16384;
  const float* BTb = BT + (size_t)b * 128;
  const int ty = tid >> 4, tx = tid & 15;
  const int ar = tid >> 2, ac = (tid & 3) * 4;
  float acc[4][4];
#pragma unroll
  for (int i = 0; i < 4; ++i)
#pragma unroll
    for (int j = 0; j < 4; ++j) acc[i][j] = 0.0f;

  for (int k0 = 0; k0 < 128; k0 += 16) {
    float4 av = *(const float4*)(Ab + (size_t)(bm + ar) * 128 + k0 + ac);
    float4 bv = *(const float4*)(BTb + (size_t)(bn + ar) * 8192 + k0 + ac);
    __syncthreads();
    As[ac + 0][ar] = av.x; As[ac + 1][ar] = av.y; As[ac + 2][ar] = av.z; As[ac + 3][ar] = av.w;
    Bs[ac + 0][ar] = bv.x; Bs[ac + 1][ar] = bv.y; Bs[ac + 2][ar] = bv.z; Bs[ac + 3][ar] = bv.w;
    __syncthreads();
#pragma unroll
    for (int kk = 0; kk < 16; ++kk) {
      float a[4], bb[4];
      *(float4*)a  = *(const float4*)&As[kk][ty * 4];
      *(float4*)bb = *(const float4*)&Bs[kk][tx * 4];
#pragma unroll
      for (int i = 0; i < 4; ++i)
#pragma unroll
        for (int j = 0; j < 4; ++j)
          acc[i][j] = fmaf(a[i], bb[j], acc[i][j]);
    }
  }
#pragma unroll
  for (int i = 0; i < 4; ++i) {
    int row = b * 128 + bm + ty * 4 + i;
    float4 v;
    v.x = acc[i][0] > 0.0f ? acc[i][0] : expm1f(acc[i][0]);
    v.y = acc[i][1] > 0.0f ? acc[i][1] : expm1f(acc[i][1]);
    v.z = acc[i][2] > 0.0f ? acc[i][2] : expm1f(acc[i][2]);
    v.w = acc[i][3] > 0.0f ? acc[i][3] : expm1f(acc[i][3]);
    *(float4*)(C + (size_t)row * 512 + bn + tx * 4) = v;
  }
}

// ---------------------------------------------------------------------------
// logits = x2 @ fin_w + fin_b  (one wave per row)
// ---------------------------------------------------------------------------
__global__ __launch_bounds__(256) void logits_kernel(
    const float* __restrict__ X, const float* __restrict__ w,
    const float* __restrict__ bptr, float* __restrict__ out, int R)
{
  int wv = (blockIdx.x * 256 + threadIdx.x) >> 6;
  int lane = threadIdx.x & 63;
  if (wv >= R) return;
  const float* xr = X + (size_t)wv * 512;
  float s = 0.0f;
#pragma unroll
  for (int i = 0; i < 8; ++i) {
    int c = lane + i * 64;
    s = fmaf(xr[c], w[c], s);
  }
  for (int off = 32; off; off >>= 1) s += __shfl_down(s, off);
  if (lane == 0) out[wv] = s + bptr[0];
}

// ---------------------------------------------------------------------------
// Final: scores -> stable rank -> gather fix -> expand.
// ---------------------------------------------------------------------------
__global__ __launch_bounds__(128) void finalize_kernel(
    const float* __restrict__ logits, const float* __restrict__ tag,
    const float* __restrict__ amask, const int* __restrict__ ig,
    int* __restrict__ out)
{
  const int b = blockIdx.x, tid = threadIdx.x;
  __shared__ float red[N_];
  __shared__ float scs[N_];
  __shared__ int fs[N_], fe[N_], lens[N_], csum[N_];
  __shared__ int redi[N_];

  float lg = logits[b * N_ + tid];
  float tg = tag[b * N_ + tid];
  float am = amask[b * N_ + tid];
  float m = (tg > 0.0f) ? am : 0.0f;

  float in1 = (m > 0.0f) ? lg * m : NEG_S_;
  red[tid] = in1; __syncthreads();
  for (int s = 64; s > 0; s >>= 1) { if (tid < s) red[tid] = fmaxf(red[tid], red[tid + s]); __syncthreads(); }
  float M1 = red[0]; __syncthreads();
  float e1 = expf(in1 - M1);
  red[tid] = e1; __syncthreads();
  for (int s = 64; s > 0; s >>= 1) { if (tid < s) red[tid] += red[tid + s]; __syncthreads(); }
  float S1 = red[0]; __syncthreads();
  float sc = e1 / S1;

  red[tid] = m; __syncthreads();
  for (int s = 64; s > 0; s >>= 1) { if (tid < s) red[tid] += red[tid + s]; __syncthreads(); }
  float SM = red[0]; __syncthreads();

  float in2 = (m > 0.0f) ? ((float)(N_ - tid) / SM) * m : NEG_S_;
  red[tid] = in2; __syncthreads();
  for (int s = 64; s > 0; s >>= 1) { if (tid < s) red[tid] = fmaxf(red[tid], red[tid + s]); __syncthreads(); }
  float M2 = red[0]; __syncthreads();
  float e2 = expf(in2 - M2);
  red[tid] = e2; __syncthreads();
  for (int s = 64; s > 0; s >>= 1) { if (tid < s) red[tid] += red[tid + s]; __syncthreads(); }
  float S2 = red[0]; __syncthreads();
  float ii = e2 / S2;

  scs[tid] = sc + ii;
  __syncthreads();

  float si = scs[tid];
  int rank = 0;
  for (int j = 0; j < N_; ++j) {
    float sj = scs[j];
    rank += (sj > si) || (sj == si && j < tid);
  }
  fs[tid] = ig[(b * N_ + rank) * 2 + 0];
  fe[tid] = ig[(b * N_ + rank) * 2 + 1];
  __syncthreads();

  redi[tid] = (fs[tid] == 0 && fe[tid] == 0) ? tid : N_;
  __syncthreads();
  for (int s = 64; s > 0; s >>= 1) { if (tid < s) redi[tid] = min(redi[tid], redi[tid + s]); __syncthreads(); }
  int fz = redi[0]; __syncthreads();
  lens[tid] = (tid < fz) ? (fe[tid] - fs[tid]) : 0;
  __syncthreads();
  if (tid == 0) {
    int r = 0;
    for (int k = 0; k < N_; ++k) { r += lens[k]; csum[k] = r; }
  }
  __syncthreads();
  int total = csum[N_ - 1];
  int l = tid;
  int k = 0;
  while (k < N_ && csum[k] <= l) ++k;
  if (k > N_ - 1) k = N_ - 1;
  int val = fs[k] + (l - (csum[k] - lens[k]));
  out[b * N_ + l] = (l < total) ? val : l;
}

// ---------------------------------------------------------------------------
extern "C" void kernel_launch(void* const* d_in, const int* in_sizes, int n_in,
                              void* d_out, int out_size, void* d_ws, size_t ws_size,
                              hipStream_t stream)
{
  const float* x     = (const float*)d_in[0];
  const float* tag   = (const float*)d_in[1];
  const int*   offs  = (const int*)  d_in[2];
  const float* amask = (const float*)d_in[3];
  const float* adj   = (const float*)d_in[4];
  const float* Wg_w  = (const float*)d_in[5];
  const float* Wg_b  = (const float*)d_in[6];
  const float* hW_w  = (const float*)d_in[7];
  const float* hW_b  = (const float*)d_in[8];
  const float* ha_w  = (const float*)d_in[9];
  const float* ha_b  = (const float*)d_in[10];
  const float* oW_w  = (const float*)d_in[11];
  const float* oW_b  = (const float*)d_in[12];
  const float* oa_w  = (const float*)d_in[13];
  const float* oa_b  = (const float*)d_in[14];
  const float* fin_w = (const float*)d_in[15];
  const float* fin_b = (const float*)d_in[16];
  int* out = (int*)d_out;

  // ---- workspace: 138.1 MB (R6/R7-proven layout) ----
  char* ws = (char*)d_ws;
  size_t o = 0;
  int* ig     = (int*)(ws + o);  o += 131072;
  u16* WgT_h  = (u16*)(ws + o);  o += 1572864;
  u16* WgT_l  = (u16*)(ws + o);  o += 1572864;
  u16* hWT_h  = (u16*)(ws + o);  o += 8388608;
  u16* hWT_l  = (u16*)(ws + o);  o += 8388608;
  u16* oWT_h  = (u16*)(ws + o);  o += 4194304;
  u16* oWT_l  = (u16*)(ws + o);  o += 4194304;
  float* h2T  = (float*)(ws + o); o += 16777216;
  float* esrc = (float*)(ws + o); o += 65536;
  float* edst = (float*)(ws + o); o += 65536;
  float* e2s  = (float*)(ws + o); o += 32768;
  float* e2d  = (float*)(ws + o); o += 32768;
  float* lgts = (float*)(ws + o); o += 32768;
  float* ps   = (float*)(ws + o); o += 16777216;
  char* pool  = ws + o;          o += 81788928;

  u16* hT_h   = (u16*)(pool + 0);
  u16* hT_l   = (u16*)(pool + 16777216);
  u16* x1_h   = (u16*)(pool + 33554432);
  u16* x1_l   = (u16*)(pool + 50331648);
  char* sub   = pool + 67108864;
  u16* xoff_h = (u16*)(sub + 0);
  u16* xoff_l = (u16*)(sub + 3145728);
  u16* xw_h   = (u16*)(sub + 6291456);
  u16* xw_l   = (u16*)(sub + 10485760);
  u16* att_h  = (u16*)(sub + 0);
  u16* att_l  = (u16*)(sub + 4194304);
  float* att2 = (float*)(pool + 0);
  float* x2   = (float*)(pool + 4194304);

  pack_wgT<<<3072, 256, 0, stream>>>(Wg_w, WgT_h, WgT_l);
  pack_hwT<<<16384, 256, 0, stream>>>(hW_w, hWT_h, hWT_l);
  pack_owT<<<8192, 256, 0, stream>>>(oW_w, oWT_h, oWT_l);

  for (int b0 = 0; b0 < B_; b0 += CHUNK_) {
    group_pool_kernel<<<dim3(CHUNK_, 6), 128, 0, stream>>>(
        x + (size_t)b0 * 98304, offs + b0 * 256, xoff_h, xoff_l, ig + b0 * 256);

    // G2 (swapped, split-K=2): M=1024(feat),N=2048(node),K=384/slice
    mfma_split_gemm<<<dim3(16, 8, 2), 256, 0, stream>>>(
        WgT_h, WgT_l, xoff_h, xoff_l, nullptr, 0,
        nullptr, nullptr, ps, 1, 0,
        384, 768, 768, 384, 384,
        10, 0, 13, 0, 1024, 0, 2097152, 2);
    reduce2_split<<<2048, 256, 0, stream>>>(ps, Wg_b, xw_h, xw_l);

    // G3: M=2048,N=4096,K=1024
    mfma_split_gemm<<<dim3(32, 16, 1), 256, 0, stream>>>(
        xw_h, xw_l, hWT_h, hWT_l, hW_b, 1,
        hT_h, hT_l, nullptr, 0, 0,
        1024, 1024, 1024, 0, 0,
        7, 524288, 9, 65536, 128, 0, 0, 1);

    dot_pairs_hT<<<CHUNK_ * 8, 512, 0, stream>>>(hT_h, hT_l, ha_w, esrc, edst);
    edge_softmax_kernel<<<CHUNK_ * 8 * 128, 64, 0, stream>>>(
        esrc, edst, ha_b, adj + (size_t)b0 * 16384, nullptr, att_h, att_l, 8, 1);

    // x1T: per z=(bc,h): M=512(o),N=128(i),K=128(j)
    mfma_split_gemm<<<dim3(1, 4, CHUNK_ * 8), 256, 0, stream>>>(
        hT_h, hT_l, att_h, att_l, nullptr, 0,
        x1_h, x1_l, nullptr, 0, 1,
        128, 128, 128, 65536, 16384,
        9, 0, 7, 0, 4096, 524288, 512, 8);

    // G7 (split-K=4): M=2048,N=512,K=1024/slice
    mfma_split_gemm<<<dim3(4, 16, 4), 256, 0, stream>>>(
        x1_h, x1_l, oWT_h, oWT_l, nullptr, 0,
        nullptr, nullptr, ps, 1, 0,
        1024, 4096, 4096, 1024, 1024,
        13, 0, 9, 0, 2048, 0, 1048576, 4);
    reduce4_bias<<<1024, 256, 0, stream>>>(ps, oW_b, h2T, b0 * 128);
  }

  // attention-2 (fp32, unchunked)
  dot_pairs_h2T<<<64, 512, 0, stream>>>(h2T, oa_w, e2s, e2d);
  edge_softmax_kernel<<<8192, 64, 0, stream>>>(e2s, e2d, oa_b, adj,
      att2, nullptr, nullptr, 1, 0);
  bgemm_elu_bt_f32<<<dim3(16, 64), 256, 0, stream>>>(att2, h2T, x2);

  // logits + finalize
  logits_kernel<<<2048, 256, 0, stream>>>(x2, fin_w, fin_b, lgts, 8192);
  finalize_kernel<<<B_, 128, 0, stream>>>(lgts, tag, amask, ig, out);
}

// Round 9
// 876.486 us; speedup vs baseline: 1.2903x; 1.2903x over previous
//
#include <hip/hip_runtime.h>
#include <cstddef>
#include <cstdint>

#define B_ 64
#define N_ 128
#define FIN_ 768
#define NEG_E_ (-9.0e15f)
#define NEG_S_ (-9.0e10f)
#define CHUNK_ 16

typedef unsigned short u16;
typedef unsigned int u32;
typedef float f32x4 __attribute__((ext_vector_type(4)));
typedef short s16x8 __attribute__((ext_vector_type(8)));   // 8 bf16 frag
typedef u16 u16x4 __attribute__((ext_vector_type(4)));

__device__ __forceinline__ u16 f2bf(float x) {
  u32 u = __float_as_uint(x);
  return (u16)((u + 0x7fffu + ((u >> 16) & 1u)) >> 16);
}
__device__ __forceinline__ float b2f(u16 h) {
  return __uint_as_float(((u32)h) << 16);
}

// ---------------------------------------------------------------------------
// Group pooling, k-sequential scan form (R7-verified). Full batch.
// ---------------------------------------------------------------------------
__global__ __launch_bounds__(128) void group_pool_kernel(
    const float* __restrict__ x, const int* __restrict__ offs,
    u16* __restrict__ xoh, u16* __restrict__ xol, int* __restrict__ ig)
{
  const int b = blockIdx.x;
  const int fc = blockIdx.y;
  const int tid = threadIdx.x;
  __shared__ int o0[N_], o1[N_];
  __shared__ int bnd[N_];
  __shared__ float invlen[N_];
  __shared__ int st[N_], en[N_];
  __shared__ int Gs;
  o0[tid] = offs[(b * N_ + tid) * 2 + 0];
  o1[tid] = offs[(b * N_ + tid) * 2 + 1];
  bnd[tid] = -1;
  __syncthreads();
  if (tid == 0) {
    int fz = N_;
    for (int k = 0; k < N_; ++k) { if (o0[k] == 0 && o1[k] == 0) { fz = k; break; } }
    int g = 0, prev = 0;
    for (int k = 0; k < fz; ++k) {
      int nxt = (k + 1 < N_) ? o0[k + 1] : 0;
      if (o1[k] == nxt - 1 && g < N_) {
        bnd[k] = g;
        invlen[g] = 1.0f / (float)(k + 1 - prev);
        st[g] = prev;
        en[g] = k + 1;
        prev = k + 1;
        ++g;
      }
    }
    Gs = g;
  }
  __syncthreads();
  const int G = Gs;
  const int f = fc * 128 + tid;
  const float* xb = x + (size_t)b * N_ * FIN_ + f;
  float acc = 0.0f;
  for (int k0 = 0; k0 < N_; k0 += 8) {
    float v[8];
#pragma unroll
    for (int u = 0; u < 8; ++u) v[u] = xb[(size_t)(k0 + u) * FIN_];
#pragma unroll
    for (int u = 0; u < 8; ++u) {
      acc += v[u];
      int g = bnd[k0 + u];
      if (g >= 0) {
        float mean = acc * invlen[g];
        u16 hh = f2bf(mean);
        size_t oo = ((size_t)b * N_ + g) * FIN_ + f;
        xoh[oo] = hh;
        xol[oo] = f2bf(mean - b2f(hh));
        acc = 0.0f;
      }
    }
  }
  for (int g = G; g < N_; ++g) {
    size_t oo = ((size_t)b * N_ + g) * FIN_ + f;
    xoh[oo] = 0;
    xol[oo] = 0;
  }
  if (fc == 0) {
    int g = tid;
    ig[(b * N_ + g) * 2 + 0] = (g < G) ? st[g] : 0;
    ig[(b * N_ + g) * 2 + 1] = (g < G) ? en[g] : 0;
  }
}

// ---------------------------------------------------------------------------
// Weight pack kernels: LDS-tiled transpose (32x32, +1 pad) -> coalesced
// reads AND writes (the R8 scatter versions had ~32x write amplification).
// ---------------------------------------------------------------------------
__global__ __launch_bounds__(256) void pack_wgT(  // Wg_w[768][1024] -> WgT[1024][768]
    const float* __restrict__ w, u16* __restrict__ th, u16* __restrict__ tl)
{
  __shared__ float t[32][33];
  const int k0 = blockIdx.x * 32, n0 = blockIdx.y * 32;
  const int r = threadIdx.x >> 3;
  const int c = (threadIdx.x & 7) * 4;
  float4 v = *(const float4*)(w + (size_t)(k0 + r) * 1024 + n0 + c);
  t[r][c] = v.x; t[r][c + 1] = v.y; t[r][c + 2] = v.z; t[r][c + 3] = v.w;
  __syncthreads();
  u16x4 hv, lv;
#pragma unroll
  for (int i = 0; i < 4; ++i) {
    float xv = t[c + i][r];
    u16 h = f2bf(xv);
    hv[i] = h; lv[i] = f2bf(xv - b2f(h));
  }
  size_t dst = (size_t)(n0 + r) * 768 + k0 + c;
  *(u16x4*)(th + dst) = hv;
  *(u16x4*)(tl + dst) = lv;
}
__global__ __launch_bounds__(256) void pack_hwT(  // hW_w[8][1024][512] -> hWT[4096][1024]
    const float* __restrict__ w, u16* __restrict__ th, u16* __restrict__ tl)
{
  __shared__ float t[32][33];
  const int o0 = blockIdx.x * 32, f0 = blockIdx.y * 32, hd = blockIdx.z;
  const int r = threadIdx.x >> 3;
  const int c = (threadIdx.x & 7) * 4;
  float4 v = *(const float4*)(w + ((size_t)hd * 1024 + f0 + r) * 512 + o0 + c);
  t[r][c] = v.x; t[r][c + 1] = v.y; t[r][c + 2] = v.z; t[r][c + 3] = v.w;
  __syncthreads();
  u16x4 hv, lv;
#pragma unroll
  for (int i = 0; i < 4; ++i) {
    float xv = t[c + i][r];
    u16 h = f2bf(xv);
    hv[i] = h; lv[i] = f2bf(xv - b2f(h));
  }
  size_t dst = ((size_t)hd * 512 + o0 + r) * 1024 + f0 + c;
  *(u16x4*)(th + dst) = hv;
  *(u16x4*)(tl + dst) = lv;
}
__global__ __launch_bounds__(256) void pack_owT(  // oW_w[4096][512] -> oWT[512][4096]
    const float* __restrict__ w, u16* __restrict__ th, u16* __restrict__ tl)
{
  __shared__ float t[32][33];
  const int k0 = blockIdx.x * 32, o0 = blockIdx.y * 32;
  const int r = threadIdx.x >> 3;
  const int c = (threadIdx.x & 7) * 4;
  float4 v = *(const float4*)(w + (size_t)(k0 + r) * 512 + o0 + c);
  t[r][c] = v.x; t[r][c + 1] = v.y; t[r][c + 2] = v.z; t[r][c + 3] = v.w;
  __syncthreads();
  u16x4 hv, lv;
#pragma unroll
  for (int i = 0; i < 4; ++i) {
    float xv = t[c + i][r];
    u16 h = f2bf(xv);
    hv[i] = h; lv[i] = f2bf(xv - b2f(h));
  }
  size_t dst = (size_t)(o0 + r) * 4096 + k0 + c;
  *(u16x4*)(th + dst) = hv;
  *(u16x4*)(tl + dst) = lv;
}

// ---------------------------------------------------------------------------
// Split-bf16 MFMA GEMM, register-prefetch pipeline + LDS-transpose epilogue
// (R8-verified).
// ---------------------------------------------------------------------------
__global__ __launch_bounds__(256) void mfma_split_gemm(
    const u16* __restrict__ Ah, const u16* __restrict__ Al,
    const u16* __restrict__ Bh, const u16* __restrict__ Bl,
    const float* __restrict__ bias, int bias_mode,   // 0 none, 1 per-n, 2 per-m
    u16* __restrict__ Oh, u16* __restrict__ Ol, float* __restrict__ Of,
    int out_f32, int do_elu,
    int K, int lda, int ldb,
    long long Az, long long Bz,
    int msh, long long s_mb, int nsh, long long s_nb, long long s_n,
    long long zb_s, long long zh_s, int zH)
{
  __shared__ u16 As_h[128][40];
  __shared__ u16 As_l[128][40];
  __shared__ u16 Bs_h[128][40];
  __shared__ u16 Bs_l[128][40];
  const int tid = threadIdx.x;
  const int wave = tid >> 6, lane = tid & 63;
  const int wm = (wave >> 1) * 64, wn = (wave & 1) * 64;
  const int bn = blockIdx.x * 128, bm = blockIdx.y * 128;
  const int z = blockIdx.z;
  const u16* Ahb = Ah + (long long)z * Az;
  const u16* Alb = Al + (long long)z * Az;
  const u16* Bhb = Bh + (long long)z * Bz;
  const u16* Blb = Bl + (long long)z * Bz;
  const int lm = lane & 15, lq = lane >> 4;

  const int sr = tid >> 1;
  const int sc = (tid & 1) * 16;
  const size_t ga = (size_t)(bm + sr) * lda + sc;
  const size_t gb = (size_t)(bn + sr) * ldb + sc;

  f32x4 acc[4][4];
#pragma unroll
  for (int i = 0; i < 4; ++i)
#pragma unroll
    for (int j = 0; j < 4; ++j) acc[i][j] = (f32x4){0.0f, 0.0f, 0.0f, 0.0f};

  uint4 r0, r1, r2, r3, r4, r5, r6, r7;
  r0 = *(const uint4*)(Ahb + ga);
  r1 = *(const uint4*)(Ahb + ga + 8);
  r2 = *(const uint4*)(Alb + ga);
  r3 = *(const uint4*)(Alb + ga + 8);
  r4 = *(const uint4*)(Bhb + gb);
  r5 = *(const uint4*)(Bhb + gb + 8);
  r6 = *(const uint4*)(Blb + gb);
  r7 = *(const uint4*)(Blb + gb + 8);

  for (int k0 = 0; k0 < K; k0 += 32) {
    __syncthreads();
    *(uint4*)&As_h[sr][sc] = r0;
    *(uint4*)&As_h[sr][sc + 8] = r1;
    *(uint4*)&As_l[sr][sc] = r2;
    *(uint4*)&As_l[sr][sc + 8] = r3;
    *(uint4*)&Bs_h[sr][sc] = r4;
    *(uint4*)&Bs_h[sr][sc + 8] = r5;
    *(uint4*)&Bs_l[sr][sc] = r6;
    *(uint4*)&Bs_l[sr][sc + 8] = r7;
    __syncthreads();
    int kn = k0 + 32;
    if (kn < K) {
      r0 = *(const uint4*)(Ahb + ga + kn);
      r1 = *(const uint4*)(Ahb + ga + kn + 8);
      r2 = *(const uint4*)(Alb + ga + kn);
      r3 = *(const uint4*)(Alb + ga + kn + 8);
      r4 = *(const uint4*)(Bhb + gb + kn);
      r5 = *(const uint4*)(Bhb + gb + kn + 8);
      r6 = *(const uint4*)(Blb + gb + kn);
      r7 = *(const uint4*)(Blb + gb + kn + 8);
    }
    s16x8 fa_h[4], fa_l[4], fb_h[4], fb_l[4];
#pragma unroll
    for (int t = 0; t < 4; ++t) {
      fa_h[t] = *(const s16x8*)&As_h[wm + t * 16 + lm][lq * 8];
      fa_l[t] = *(const s16x8*)&As_l[wm + t * 16 + lm][lq * 8];
      fb_h[t] = *(const s16x8*)&Bs_h[wn + t * 16 + lm][lq * 8];
      fb_l[t] = *(const s16x8*)&Bs_l[wn + t * 16 + lm][lq * 8];
    }
#pragma unroll
    for (int i = 0; i < 4; ++i)
#pragma unroll
      for (int j = 0; j < 4; ++j) {
        acc[i][j] = __builtin_amdgcn_mfma_f32_16x16x32_bf16(fa_h[i], fb_h[j], acc[i][j], 0, 0, 0);
        acc[i][j] = __builtin_amdgcn_mfma_f32_16x16x32_bf16(fa_h[i], fb_l[j], acc[i][j], 0, 0, 0);
        acc[i][j] = __builtin_amdgcn_mfma_f32_16x16x32_bf16(fa_l[i], fb_h[j], acc[i][j], 0, 0, 0);
      }
  }

  // ---- LDS-transpose epilogue ----
  __syncthreads();
  const long long zoff = (long long)(z / zH) * zb_s + (long long)(z % zH) * zh_s;
  const int mmask = (1 << msh) - 1;
  const int nmask = (1 << nsh) - 1;
  char* lds_raw = (char*)&As_h[0][0] + wave * 4608;
  const int rn = lane >> 2;
  const int rm = (lane & 3) * 16;

  if (out_f32) {
    float* slab = (float*)lds_raw;      // [16][68]
#pragma unroll
    for (int j = 0; j < 4; ++j) {
#pragma unroll
      for (int i = 0; i < 4; ++i) {
        int mb = bm + wm + i * 16 + lq * 4;
        int n = bn + wn + j * 16 + lm;
        f32x4 v = acc[i][j];
        if (bias_mode == 1) v += bias[n];
        else if (bias_mode == 2) { f32x4 b4 = *(const f32x4*)&bias[mb]; v += b4; }
        if (do_elu) {
          v.x = v.x > 0.0f ? v.x : expm1f(v.x);
          v.y = v.y > 0.0f ? v.y : expm1f(v.y);
          v.z = v.z > 0.0f ? v.z : expm1f(v.z);
          v.w = v.w > 0.0f ? v.w : expm1f(v.w);
        }
        *(f32x4*)&slab[lm * 68 + i * 16 + lq * 4] = v;
      }
      __syncthreads();
      int n = bn + wn + j * 16 + rn;
      int mbase = bm + wm + rm;
      long long off = (long long)(mbase >> msh) * s_mb + (mbase & mmask)
                    + (long long)(n >> nsh) * s_nb + (long long)(n & nmask) * s_n + zoff;
      const float* src = &slab[rn * 68 + rm];
      f32x4 v0 = *(const f32x4*)(src + 0);
      f32x4 v1 = *(const f32x4*)(src + 4);
      f32x4 v2 = *(const f32x4*)(src + 8);
      f32x4 v3 = *(const f32x4*)(src + 12);
      *(f32x4*)(Of + off + 0)  = v0;
      *(f32x4*)(Of + off + 4)  = v1;
      *(f32x4*)(Of + off + 8)  = v2;
      *(f32x4*)(Of + off + 12) = v3;
      __syncthreads();
    }
  } else {
    u16* slab_h = (u16*)lds_raw;        // [16][72]
    u16* slab_l = slab_h + 16 * 72;
#pragma unroll
    for (int j = 0; j < 4; ++j) {
#pragma unroll
      for (int i = 0; i < 4; ++i) {
        int mb = bm + wm + i * 16 + lq * 4;
        int n = bn + wn + j * 16 + lm;
        f32x4 v = acc[i][j];
        if (bias_mode == 1) v += bias[n];
        else if (bias_mode == 2) { f32x4 b4 = *(const f32x4*)&bias[mb]; v += b4; }
        if (do_elu) {
          v.x = v.x > 0.0f ? v.x : expm1f(v.x);
          v.y = v.y > 0.0f ? v.y : expm1f(v.y);
          v.z = v.z > 0.0f ? v.z : expm1f(v.z);
          v.w = v.w > 0.0f ? v.w : expm1f(v.w);
        }
        u16 h0 = f2bf(v.x), h1 = f2bf(v.y), h2 = f2bf(v.z), h3 = f2bf(v.w);
        u16x4 hv = {h0, h1, h2, h3};
        u16x4 lv = {f2bf(v.x - b2f(h0)), f2bf(v.y - b2f(h1)),
                    f2bf(v.z - b2f(h2)), f2bf(v.w - b2f(h3))};
        *(u16x4*)&slab_h[lm * 72 + i * 16 + lq * 4] = hv;
        *(u16x4*)&slab_l[lm * 72 + i * 16 + lq * 4] = lv;
      }
      __syncthreads();
      int n = bn + wn + j * 16 + rn;
      int mbase = bm + wm + rm;
      long long off = (long long)(mbase >> msh) * s_mb + (mbase & mmask)
                    + (long long)(n >> nsh) * s_nb + (long long)(n & nmask) * s_n + zoff;
      const u16* sh = &slab_h[rn * 72 + rm];
      const u16* sl = &slab_l[rn * 72 + rm];
      uint4 h0 = *(const uint4*)(sh + 0);
      uint4 h1 = *(const uint4*)(sh + 8);
      uint4 l0 = *(const uint4*)(sl + 0);
      uint4 l1 = *(const uint4*)(sl + 8);
      *(uint4*)(Oh + off + 0) = h0;
      *(uint4*)(Oh + off + 8) = h1;
      *(uint4*)(Ol + off + 0) = l0;
      *(uint4*)(Ol + off + 8) = l1;
      __syncthreads();
    }
  }
}

// ---------------------------------------------------------------------------
// Split-K reduce for G7.
// ---------------------------------------------------------------------------
__global__ __launch_bounds__(256) void reduce4_bias(
    const float* __restrict__ ps, const float* __restrict__ bias,
    float* __restrict__ h2T, int col0)
{
  int base = (blockIdx.x * 256 + threadIdx.x) * 4;   // 512*2048 elements
  int o = base >> 11, m = base & 2047;
  f32x4 v = *(const f32x4*)(ps + base);
  v += *(const f32x4*)(ps + base + 1048576);
  v += *(const f32x4*)(ps + base + 2097152);
  v += *(const f32x4*)(ps + base + 3145728);
  v += bias[o];
  *(f32x4*)(h2T + (size_t)o * 8192 + col0 + m) = v;
}

// ---------------------------------------------------------------------------
// esrc/edst from hT (split bf16): block per (bc,head), 512 threads.
// ---------------------------------------------------------------------------
__global__ __launch_bounds__(512) void dot_pairs_hT(
    const u16* __restrict__ hTh, const u16* __restrict__ hTl,
    const float* __restrict__ W,   // ha_w [8][1024]
    float* __restrict__ esrc, float* __restrict__ edst)
{
  int bh = blockIdx.x;
  int head = bh & 7;
  int tid = threadIdx.x;
  int os = tid >> 7, i = tid & 127;
  const u16* ph = hTh + (size_t)bh * 65536 + (size_t)os * 16384 + i;
  const u16* pl = hTl + (size_t)bh * 65536 + (size_t)os * 16384 + i;
  const float* w1 = W + head * 1024 + os * 128;
  float s1 = 0.0f, s2 = 0.0f;
#pragma unroll 8
  for (int o = 0; o < 128; ++o) {
    float hv = b2f(ph[o * 128]) + b2f(pl[o * 128]);
    s1 = fmaf(hv, w1[o], s1);
    s2 = fmaf(hv, w1[512 + o], s2);
  }
  __shared__ float sh1[4][128], sh2[4][128];
  sh1[os][i] = s1;
  sh2[os][i] = s2;
  __syncthreads();
  if (os == 0) {
    esrc[bh * 128 + i] = sh1[0][i] + sh1[1][i] + sh1[2][i] + sh1[3][i];
    edst[bh * 128 + i] = sh2[0][i] + sh2[1][i] + sh2[2][i] + sh2[3][i];
  }
}

// e2 dots from h2T (fp32): block per b, 512 threads.
__global__ __launch_bounds__(512) void dot_pairs_h2T(
    const float* __restrict__ h2T, const float* __restrict__ oa,
    float* __restrict__ e2s, float* __restrict__ e2d)
{
  int b = blockIdx.x;
  int tid = threadIdx.x;
  int os = tid >> 7, i = tid & 127;
  const float* hb = h2T + (size_t)os * 128 * 8192 + b * 128 + i;
  const float* oa1 = oa + os * 128;
  float s1 = 0.0f, s2 = 0.0f;
#pragma unroll 8
  for (int o = 0; o < 128; ++o) {
    float hv = hb[(size_t)o * 8192];
    s1 = fmaf(hv, oa1[o], s1);
    s2 = fmaf(hv, oa1[512 + o], s2);
  }
  __shared__ float sh1[4][128], sh2[4][128];
  sh1[os][i] = s1;
  sh2[os][i] = s2;
  __syncthreads();
  if (os == 0) {
    e2s[b * 128 + i] = sh1[0][i] + sh1[1][i] + sh1[2][i] + sh1[3][i];
    e2d[b * 128 + i] = sh2[0][i] + sh2[1][i] + sh2[2][i] + sh2[3][i];
  }
}

// ---------------------------------------------------------------------------
// Edge softmax; split=1 -> bf16 hi/lo output, else fp32.  adj pre-offset.
// ---------------------------------------------------------------------------
__global__ __launch_bounds__(64) void edge_softmax_kernel(
    const float* __restrict__ esrc, const float* __restrict__ edst,
    const float* __restrict__ bias, const float* __restrict__ adj,
    float* __restrict__ attf, u16* __restrict__ atth, u16* __restrict__ attl,
    int H, int split)
{
  int row = blockIdx.x;
  int lane = threadIdx.x;
  int i = row & 127;
  int bh = row >> 7;
  int hd = bh % H;
  int b = bh / H;
  float es = esrc[row] + bias[hd];
  const float* adjr = adj + ((size_t)b * N_ + i) * N_;
  const float* edr = edst + (size_t)bh * N_;
  float v[2];
#pragma unroll
  for (int t = 0; t < 2; ++t) {
    int j = lane + t * 64;
    float e = es + edr[j];
    e = (e >= 0.0f) ? e : 0.2f * e;
    v[t] = (adjr[j] > 0.0f) ? e : NEG_E_;
  }
  float mx = fmaxf(v[0], v[1]);
  for (int off = 32; off; off >>= 1) mx = fmaxf(mx, __shfl_xor(mx, off));
  float e0 = expf(v[0] - mx), e1 = expf(v[1] - mx);
  float sm = e0 + e1;
  for (int off = 32; off; off >>= 1) sm += __shfl_xor(sm, off);
  float inv = 1.0f / sm;
  float p0 = e0 * inv, p1 = e1 * inv;
  size_t base = (size_t)row * N_;
  if (split) {
    u16 h0 = f2bf(p0), h1 = f2bf(p1);
    atth[base + lane] = h0;
    attl[base + lane] = f2bf(p0 - b2f(h0));
    atth[base + lane + 64] = h1;
    attl[base + lane + 64] = f2bf(p1 - b2f(h1));
  } else {
    attf[base + lane] = p0;
    attf[base + lane + 64] = p1;
  }
}

// ---------------------------------------------------------------------------
// Stage-2 fp32 batched GEMM + ELU (h2T[512][8192] B-layout).
// ---------------------------------------------------------------------------
__global__ __launch_bounds__(256) void bgemm_elu_bt_f32(
    const float* __restrict__ A, const float* __restrict__ BT,
    float* __restrict__ C)
{
  __shared__ float As[16][64];
  __shared__ float Bs[16][68];
  const int tid = threadIdx.x;
  const int tm = blockIdx.x >> 3, tn = blockIdx.x & 7;
  const int bm = tm * 64, bn = tn * 64;
  const int b = blockIdx.y;
  const float* Ab = A + (size_t)b * 16384;
  const float* BTb = BT + (size_t)b * 128;
  const int ty = tid >> 4, tx = tid & 15;
  const int ar = tid >> 2, ac = (tid & 3) * 4;
  float acc[4][4];
#pragma unroll
  for (int i = 0; i < 4; ++i)
#pragma unroll
    for (int j = 0; j < 4; ++j) acc[i][j] = 0.0f;

  for (int k0 = 0; k0 < 128; k0 += 16) {
    float4 av = *(const float4*)(Ab + (size_t)(bm + ar) * 128 + k0 + ac);
    float4 bv = *(const float4*)(BTb + (size_t)(bn + ar) * 8192 + k0 + ac);
    __syncthreads();
    As[ac + 0][ar] = av.x; As[ac + 1][ar] = av.y; As[ac + 2][ar] = av.z; As[ac + 3][ar] = av.w;
    Bs[ac + 0][ar] = bv.x; Bs[ac + 1][ar] = bv.y; Bs[ac + 2][ar] = bv.z; Bs[ac + 3][ar] = bv.w;
    __syncthreads();
#pragma unroll
    for (int kk = 0; kk < 16; ++kk) {
      float a[4], bb[4];
      *(float4*)a  = *(const float4*)&As[kk][ty * 4];
      *(float4*)bb = *(const float4*)&Bs[kk][tx * 4];
#pragma unroll
      for (int i = 0; i < 4; ++i)
#pragma unroll
        for (int j = 0; j < 4; ++j)
          acc[i][j] = fmaf(a[i], bb[j], acc[i][j]);
    }
  }
#pragma unroll
  for (int i = 0; i < 4; ++i) {
    int row = b * 128 + bm + ty * 4 + i;
    float4 v;
    v.x = acc[i][0] > 0.0f ? acc[i][0] : expm1f(acc[i][0]);
    v.y = acc[i][1] > 0.0f ? acc[i][1] : expm1f(acc[i][1]);
    v.z = acc[i][2] > 0.0f ? acc[i][2] : expm1f(acc[i][2]);
    v.w = acc[i][3] > 0.0f ? acc[i][3] : expm1f(acc[i][3]);
    *(float4*)(C + (size_t)row * 512 + bn + tx * 4) = v;
  }
}

// ---------------------------------------------------------------------------
// logits = x2 @ fin_w + fin_b  (one wave per row)
// ---------------------------------------------------------------------------
__global__ __launch_bounds__(256) void logits_kernel(
    const float* __restrict__ X, const float* __restrict__ w,
    const float* __restrict__ bptr, float* __restrict__ out, int R)
{
  int wv = (blockIdx.x * 256 + threadIdx.x) >> 6;
  int lane = threadIdx.x & 63;
  if (wv >= R) return;
  const float* xr = X + (size_t)wv * 512;
  float s = 0.0f;
#pragma unroll
  for (int i = 0; i < 8; ++i) {
    int c = lane + i * 64;
    s = fmaf(xr[c], w[c], s);
  }
  for (int off = 32; off; off >>= 1) s += __shfl_down(s, off);
  if (lane == 0) out[wv] = s + bptr[0];
}

// ---------------------------------------------------------------------------
// Final: scores -> stable rank -> gather fix -> expand.
// ---------------------------------------------------------------------------
__global__ __launch_bounds__(128) void finalize_kernel(
    const float* __restrict__ logits, const float* __restrict__ tag,
    const float* __restrict__ amask, const int* __restrict__ ig,
    int* __restrict__ out)
{
  const int b = blockIdx.x, tid = threadIdx.x;
  __shared__ float red[N_];
  __shared__ float scs[N_];
  __shared__ int fs[N_], fe[N_], lens[N_], csum[N_];
  __shared__ int redi[N_];

  float lg = logits[b * N_ + tid];
  float tg = tag[b * N_ + tid];
  float am = amask[b * N_ + tid];
  float m = (tg > 0.0f) ? am : 0.0f;

  float in1 = (m > 0.0f) ? lg * m : NEG_S_;
  red[tid] = in1; __syncthreads();
  for (int s = 64; s > 0; s >>= 1) { if (tid < s) red[tid] = fmaxf(red[tid], red[tid + s]); __syncthreads(); }
  float M1 = red[0]; __syncthreads();
  float e1 = expf(in1 - M1);
  red[tid] = e1; __syncthreads();
  for (int s = 64; s > 0; s >>= 1) { if (tid < s) red[tid] += red[tid + s]; __syncthreads(); }
  float S1 = red[0]; __syncthreads();
  float sc = e1 / S1;

  red[tid] = m; __syncthreads();
  for (int s = 64; s > 0; s >>= 1) { if (tid < s) red[tid] += red[tid + s]; __syncthreads(); }
  float SM = red[0]; __syncthreads();

  float in2 = (m > 0.0f) ? ((float)(N_ - tid) / SM) * m : NEG_S_;
  red[tid] = in2; __syncthreads();
  for (int s = 64; s > 0; s >>= 1) { if (tid < s) red[tid] = fmaxf(red[tid], red[tid + s]); __syncthreads(); }
  float M2 = red[0]; __syncthreads();
  float e2 = expf(in2 - M2);
  red[tid] = e2; __syncthreads();
  for (int s = 64; s > 0; s >>= 1) { if (tid < s) red[tid] += red[tid + s]; __syncthreads(); }
  float S2 = red[0]; __syncthreads();
  float ii = e2 / S2;

  scs[tid] = sc + ii;
  __syncthreads();

  float si = scs[tid];
  int rank = 0;
  for (int j = 0; j < N_; ++j) {
    float sj = scs[j];
    rank += (sj > si) || (sj == si && j < tid);
  }
  fs[tid] = ig[(b * N_ + rank) * 2 + 0];
  fe[tid] = ig[(b * N_ + rank) * 2 + 1];
  __syncthreads();

  redi[tid] = (fs[tid] == 0 && fe[tid] == 0) ? tid : N_;
  __syncthreads();
  for (int s = 64; s > 0; s >>= 1) { if (tid < s) redi[tid] = min(redi[tid], redi[tid + s]); __syncthreads(); }
  int fz = redi[0]; __syncthreads();
  lens[tid] = (tid < fz) ? (fe[tid] - fs[tid]) : 0;
  __syncthreads();
  if (tid == 0) {
    int r = 0;
    for (int k = 0; k < N_; ++k) { r += lens[k]; csum[k] = r; }
  }
  __syncthreads();
  int total = csum[N_ - 1];
  int l = tid;
  int k = 0;
  while (k < N_ && csum[k] <= l) ++k;
  if (k > N_ - 1) k = N_ - 1;
  int val = fs[k] + (l - (csum[k] - lens[k]));
  out[b * N_ + l] = (l < total) ? val : l;
}

// ---------------------------------------------------------------------------
extern "C" void kernel_launch(void* const* d_in, const int* in_sizes, int n_in,
                              void* d_out, int out_size, void* d_ws, size_t ws_size,
                              hipStream_t stream)
{
  const float* x     = (const float*)d_in[0];
  const float* tag   = (const float*)d_in[1];
  const int*   offs  = (const int*)  d_in[2];
  const float* amask = (const float*)d_in[3];
  const float* adj   = (const float*)d_in[4];
  const float* Wg_w  = (const float*)d_in[5];
  const float* Wg_b  = (const float*)d_in[6];
  const float* hW_w  = (const float*)d_in[7];
  const float* hW_b  = (const float*)d_in[8];
  const float* ha_w  = (const float*)d_in[9];
  const float* ha_b  = (const float*)d_in[10];
  const float* oW_w  = (const float*)d_in[11];
  const float* oW_b  = (const float*)d_in[12];
  const float* oa_w  = (const float*)d_in[13];
  const float* oa_b  = (const float*)d_in[14];
  const float* fin_w = (const float*)d_in[15];
  const float* fin_b = (const float*)d_in[16];
  int* out = (int*)d_out;

  // ---- workspace: 154.5 MB (< proven-safe 197.5 MB) ----
  char* ws = (char*)d_ws;
  size_t o = 0;
  int* ig     = (int*)(ws + o);  o += 131072;
  u16* WgT_h  = (u16*)(ws + o);  o += 1572864;
  u16* WgT_l  = (u16*)(ws + o);  o += 1572864;
  u16* hWT_h  = (u16*)(ws + o);  o += 8388608;
  u16* hWT_l  = (u16*)(ws + o);  o += 8388608;
  u16* oWT_h  = (u16*)(ws + o);  o += 4194304;
  u16* oWT_l  = (u16*)(ws + o);  o += 4194304;
  float* h2T  = (float*)(ws + o); o += 16777216;
  float* esrc = (float*)(ws + o); o += 65536;
  float* edst = (float*)(ws + o); o += 65536;
  float* e2s  = (float*)(ws + o); o += 32768;
  float* e2d  = (float*)(ws + o); o += 32768;
  float* lgts = (float*)(ws + o); o += 32768;
  u16* xw_h   = (u16*)(ws + o);  o += 16777216;   // full-batch xw (8192x1024)
  u16* xw_l   = (u16*)(ws + o);  o += 16777216;
  char* pool  = ws + o;          o += 75497472;   // overlaid region

  // pool overlays (time-sliced):
  u16* xoff_h = (u16*)(pool + 0);          // full-batch x_off (8192x768), dead after G2
  u16* xoff_l = (u16*)(pool + 12582912);
  u16* hT_h   = (u16*)(pool + 0);          // per-chunk hT (dead after x1T)
  u16* hT_l   = (u16*)(pool + 16777216);
  u16* x1_h   = (u16*)(pool + 33554432);   // per-chunk x1
  u16* x1_l   = (u16*)(pool + 50331648);
  u16* att_h  = (u16*)(pool + 67108864);   // per-chunk att
  u16* att_l  = (u16*)(pool + 71303168);
  float* ps   = (float*)(pool + 0);        // G7 split-K partials (overlays dead hT)
  float* att2 = (float*)(pool + 0);        // stage-2 tail
  float* x2   = (float*)(pool + 4194304);

  // weight packing (LDS-tiled transpose, coalesced both sides)
  pack_wgT<<<dim3(24, 32), 256, 0, stream>>>(Wg_w, WgT_h, WgT_l);
  pack_hwT<<<dim3(16, 32, 8), 256, 0, stream>>>(hW_w, hWT_h, hWT_l);
  pack_owT<<<dim3(128, 16), 256, 0, stream>>>(oW_w, oWT_h, oWT_l);

  // full-batch group pool -> x_off (split), ig
  group_pool_kernel<<<dim3(B_, 6), 128, 0, stream>>>(x, offs, xoff_h, xoff_l, ig);

  // G2 full-batch (swapped): xw[node][feat] = x_off @ Wg + Wg_b.
  // M=1024(feat), N=8192(node), K=768, 512 blocks -- no split-K needed.
  mfma_split_gemm<<<dim3(64, 8, 1), 256, 0, stream>>>(
      WgT_h, WgT_l, xoff_h, xoff_l, Wg_b, 2,
      xw_h, xw_l, nullptr, 0, 0,
      768, 768, 768, 0, 0,
      10, 0, 13, 0, 1024, 0, 0, 1);

  for (int b0 = 0; b0 < B_; b0 += CHUNK_) {
    // G3: hT[(bc*8+h)*512+o][i] = (xw @ hW + hW_b)^T. M=2048,N=4096,K=1024
    mfma_split_gemm<<<dim3(32, 16, 1), 256, 0, stream>>>(
        xw_h + (size_t)b0 * 131072, xw_l + (size_t)b0 * 131072,
        hWT_h, hWT_l, hW_b, 1,
        hT_h, hT_l, nullptr, 0, 0,
        1024, 1024, 1024, 0, 0,
        7, 524288, 9, 65536, 128, 0, 0, 1);

    dot_pairs_hT<<<CHUNK_ * 8, 512, 0, stream>>>(hT_h, hT_l, ha_w, esrc, edst);
    edge_softmax_kernel<<<CHUNK_ * 8 * 128, 64, 0, stream>>>(
        esrc, edst, ha_b, adj + (size_t)b0 * 16384, nullptr, att_h, att_l, 8, 1);

    // x1T: per z=(bc,h): M=512(o),N=128(i),K=128(j)
    mfma_split_gemm<<<dim3(1, 4, CHUNK_ * 8), 256, 0, stream>>>(
        hT_h, hT_l, att_h, att_l, nullptr, 0,
        x1_h, x1_l, nullptr, 0, 1,
        128, 128, 128, 65536, 16384,
        9, 0, 7, 0, 4096, 524288, 512, 8);

    // G7 (split-K=4): M=2048,N=512,K=1024/slice  (ps overlays dead hT)
    mfma_split_gemm<<<dim3(4, 16, 4), 256, 0, stream>>>(
        x1_h, x1_l, oWT_h, oWT_l, nullptr, 0,
        nullptr, nullptr, ps, 1, 0,
        1024, 4096, 4096, 1024, 1024,
        13, 0, 9, 0, 2048, 0, 1048576, 4);
    reduce4_bias<<<1024, 256, 0, stream>>>(ps, oW_b, h2T, b0 * 128);
  }

  // attention-2 (fp32, unchunked)
  dot_pairs_h2T<<<64, 512, 0, stream>>>(h2T, oa_w, e2s, e2d);
  edge_softmax_kernel<<<8192, 64, 0, stream>>>(e2s, e2d, oa_b, adj,
      att2, nullptr, nullptr, 1, 0);
  bgemm_elu_bt_f32<<<dim3(16, 64), 256, 0, stream>>>(att2, h2T, x2);

  // logits + finalize
  logits_kernel<<<2048, 256, 0, stream>>>(x2, fin_w, fin_b, lgts, 8192);
  finalize_kernel<<<B_, 128, 0, stream>>>(lgts, tag, amask, ig, out);
}